// Round 1
// baseline (1054.889 us; speedup 1.0000x reference)
//
#include <hip/hip_runtime.h>
#include <math.h>

#define GN 50000
#define GE 800000
#define DIN 128
#define FO 32
#define NH 8
#define HFO 256
#define NC 8

// ---------------- GEMM1: [GN,128] @ [128,256] (weights stored [H][128][32]) ----
__global__ __launch_bounds__(256) void gemm1_kernel(const float* __restrict__ X,
                                                    const float* __restrict__ W,
                                                    float* __restrict__ out) {
  __shared__ __align__(16) float As[32][132];  // transposed A tile, +4 pad
  __shared__ __align__(16) float Bs[32][128];
  const int m0 = blockIdx.x * 128;
  const int c0 = blockIdx.y * 128;
  const int tid = threadIdx.x;
  const int ty = tid >> 4, tx = tid & 15;
  const int ry = ty * 8, cx = tx * 8;
  float acc[8][8] = {};
  for (int kb = 0; kb < 4; ++kb) {
    {
      int r = tid >> 3;
      int kk = (tid & 7) * 4;
#pragma unroll
      for (int p = 0; p < 4; ++p) {
        int row = r + p * 32;
        int grow = m0 + row; if (grow > GN - 1) grow = GN - 1;
        const float4 v = *reinterpret_cast<const float4*>(X + (size_t)grow * DIN + kb * 32 + kk);
        As[kk + 0][row] = v.x; As[kk + 1][row] = v.y;
        As[kk + 2][row] = v.z; As[kk + 3][row] = v.w;
      }
#pragma unroll
      for (int p = 0; p < 4; ++p) {
        int linear = (p * 256 + tid) * 4;
        int cc = linear & 127;
        int kl = linear >> 7;
        int c = c0 + cc;
        int h = c >> 5, f = c & 31;
        const float4 v = *reinterpret_cast<const float4*>(W + h * (DIN * FO) + (kb * 32 + kl) * FO + f);
        *reinterpret_cast<float4*>(&Bs[kl][cc]) = v;
      }
    }
    __syncthreads();
#pragma unroll
    for (int k = 0; k < 32; ++k) {
      float a[8], b[8];
      *reinterpret_cast<float4*>(&a[0]) = *reinterpret_cast<const float4*>(&As[k][ry]);
      *reinterpret_cast<float4*>(&a[4]) = *reinterpret_cast<const float4*>(&As[k][ry + 4]);
      *reinterpret_cast<float4*>(&b[0]) = *reinterpret_cast<const float4*>(&Bs[k][cx]);
      *reinterpret_cast<float4*>(&b[4]) = *reinterpret_cast<const float4*>(&Bs[k][cx + 4]);
#pragma unroll
      for (int i = 0; i < 8; ++i)
#pragma unroll
        for (int j = 0; j < 8; ++j)
          acc[i][j] = fmaf(a[i], b[j], acc[i][j]);
    }
    __syncthreads();
  }
#pragma unroll
  for (int i = 0; i < 8; ++i) {
    int row = m0 + ry + i;
    if (row < GN) {
      float4 v0 = make_float4(acc[i][0], acc[i][1], acc[i][2], acc[i][3]);
      float4 v1 = make_float4(acc[i][4], acc[i][5], acc[i][6], acc[i][7]);
      float* p = out + (size_t)row * HFO + c0 + cx;
      *reinterpret_cast<float4*>(p) = v0;
      *reinterpret_cast<float4*>(p + 4) = v1;
    }
  }
}

// ---------------- per-node attention scalars (one wave per node) ----------------
__global__ __launch_bounds__(256) void node_scalar_kernel(
    const float* __restrict__ hs, const float* __restrict__ ht,
    const float* __restrict__ a1, const float* __restrict__ a2,
    float* __restrict__ s1, float* __restrict__ t1,
    float* __restrict__ s2, float* __restrict__ t2) {
  int w = (blockIdx.x * 256 + threadIdx.x) >> 6;
  int lane = threadIdx.x & 63;
  if (w >= GN) return;
  int h = lane >> 3, fq = (lane & 7) * 4;
  float4 vs = *reinterpret_cast<const float4*>(hs + (size_t)w * HFO + lane * 4);
  float4 vt = *reinterpret_cast<const float4*>(ht + (size_t)w * HFO + lane * 4);
  float4 a1lo = *reinterpret_cast<const float4*>(a1 + h * 64 + fq);
  float4 a1hi = *reinterpret_cast<const float4*>(a1 + h * 64 + 32 + fq);
  float4 a2lo = *reinterpret_cast<const float4*>(a2 + h * 64 + fq);
  float4 a2hi = *reinterpret_cast<const float4*>(a2 + h * 64 + 32 + fq);
  float ps1 = vs.x * a1lo.x + vs.y * a1lo.y + vs.z * a1lo.z + vs.w * a1lo.w;
  float pt1 = vt.x * a1hi.x + vt.y * a1hi.y + vt.z * a1hi.z + vt.w * a1hi.w;
  float pt2 = vt.x * a2lo.x + vt.y * a2lo.y + vt.z * a2lo.z + vt.w * a2lo.w;
  float ps2 = vs.x * a2hi.x + vs.y * a2hi.y + vs.z * a2hi.z + vs.w * a2hi.w;
#pragma unroll
  for (int k = 1; k < 8; k <<= 1) {
    ps1 += __shfl_xor(ps1, k);
    pt1 += __shfl_xor(pt1, k);
    pt2 += __shfl_xor(pt2, k);
    ps2 += __shfl_xor(ps2, k);
  }
  if ((lane & 7) == 0) {
    s1[w * NH + h] = ps1; t1[w * NH + h] = pt1;
    s2[w * NH + h] = ps2; t2[w * NH + h] = pt2;
  }
}

// ---------------- CSR build ----------------
__global__ __launch_bounds__(256) void count_kernel(const int* __restrict__ et,
                                                    const int* __restrict__ es,
                                                    int* cnt_t, int* cnt_s) {
  int e = blockIdx.x * 256 + threadIdx.x;
  if (e < GE) {
    atomicAdd(&cnt_t[et[e]], 1);
    atomicAdd(&cnt_s[es[e]], 1);
  }
}

__global__ __launch_bounds__(1024) void scan_kernel(const int* __restrict__ cnt,
                                                    int* __restrict__ off,
                                                    int* __restrict__ cur) {
  __shared__ int part[1024];
  const int SEG = (GN + 1023) / 1024;  // 49
  int t = threadIdx.x;
  int start = t * SEG;
  int end = start + SEG; if (end > GN) end = GN;
  int s = 0;
  for (int i = start; i < end; ++i) s += cnt[i];
  part[t] = s;
  __syncthreads();
  for (int dstep = 1; dstep < 1024; dstep <<= 1) {
    int v = part[t];
    int u = (t >= dstep) ? part[t - dstep] : 0;
    __syncthreads();
    part[t] = v + u;
    __syncthreads();
  }
  int run = (t == 0) ? 0 : part[t - 1];
  for (int i = start; i < end; ++i) { off[i] = run; cur[i] = run; run += cnt[i]; }
  if (t == 1023) off[GN] = part[1023];
}

__global__ __launch_bounds__(256) void scatter_kernel(const int* __restrict__ et,
                                                      const int* __restrict__ es,
                                                      int* cur_t, int* cur_s,
                                                      int* idx_t, int* idx_s) {
  int e = blockIdx.x * 256 + threadIdx.x;
  if (e < GE) {
    idx_t[atomicAdd(&cur_t[et[e]], 1)] = e;
    idx_s[atomicAdd(&cur_s[es[e]], 1)] = e;
  }
}

// ---------------- layer-1 aggregation: one wave per node, 8 heads x 32 feats ----
__global__ __launch_bounds__(256) void agg1_kernel(
    const int* __restrict__ off, const int* __restrict__ idx,
    const int* __restrict__ other_end,
    const float* __restrict__ sA, const float* __restrict__ sB,
    const float* __restrict__ feat, float* __restrict__ out) {
  int w = (blockIdx.x * 256 + threadIdx.x) >> 6;
  int lane = threadIdx.x & 63;
  if (w >= GN) return;
  const int beg = off[w];
  const int d = off[w + 1] - beg;
  const int h = lane >> 3;
  const float sBn = sB[w * NH + h];
  float a0 = 0.f, a1v = 0.f, a2v = 0.f, a3 = 0.f;
  if (d > 0) {
    // phase A: online max/sum, lanes j=lane&7 stride 8 over edges, per head h
    float m = -1e30f, sum = 0.f;
    for (int p = (lane & 7); p < d; p += 8) {
      int e = idx[beg + p];
      int o = other_end[e];
      float x = sA[o * NH + h] + sBn;
      x = x >= 0.f ? x : 0.1f * x;
      float nm = fmaxf(m, x);
      sum = sum * expf(m - nm) + expf(x - nm);
      m = nm;
    }
#pragma unroll
    for (int k = 1; k < 8; k <<= 1) {
      float om = __shfl_xor(m, k), os = __shfl_xor(sum, k);
      float nm = fmaxf(m, om);
      sum = sum * expf(m - nm) + os * expf(om - nm);
      m = nm;
    }
    float inv = 1.f / sum;
    // phase B: every lane walks all edges; lane owns 4 feature cols
    for (int p = 0; p < d; ++p) {
      int e = idx[beg + p];
      int o = other_end[e];
      float x = sA[o * NH + h] + sBn;
      x = x >= 0.f ? x : 0.1f * x;
      float wgt = expf(x - m) * inv;
      float4 v = *reinterpret_cast<const float4*>(feat + (size_t)o * HFO + lane * 4);
      a0 = fmaf(wgt, v.x, a0); a1v = fmaf(wgt, v.y, a1v);
      a2v = fmaf(wgt, v.z, a2v); a3 = fmaf(wgt, v.w, a3);
    }
  }
  float4 r;  // ELU (concat=True)
  r.x = a0 > 0.f ? a0 : expf(a0) - 1.f;
  r.y = a1v > 0.f ? a1v : expf(a1v) - 1.f;
  r.z = a2v > 0.f ? a2v : expf(a2v) - 1.f;
  r.w = a3 > 0.f ? a3 : expf(a3) - 1.f;
  *reinterpret_cast<float4*>(out + (size_t)w * HFO + lane * 4) = r;
}

// ---------------- layer-2 projection + logit scalars (one wave per node) -------
__global__ __launch_bounds__(256) void gemm2_kernel(
    const float* __restrict__ out_ts, const float* __restrict__ out_st,
    const float* __restrict__ Wso, const float* __restrict__ Wto,
    const float* __restrict__ a1o, const float* __restrict__ a2o,
    float* __restrict__ g_hs, float* __restrict__ g_ht,
    float* __restrict__ gs1, float* __restrict__ gt1,
    float* __restrict__ gt2, float* __restrict__ gs2) {
  __shared__ float WsL[HFO * NC], WtL[HFO * NC];
  for (int i = threadIdx.x; i < HFO * NC; i += 256) { WsL[i] = Wso[i]; WtL[i] = Wto[i]; }
  __syncthreads();
  int w = (blockIdx.x * 256 + threadIdx.x) >> 6;
  int lane = threadIdx.x & 63;
  if (w >= GN) return;
  float4 xs4 = *reinterpret_cast<const float4*>(out_ts + (size_t)w * HFO + lane * 4);
  float4 xt4 = *reinterpret_cast<const float4*>(out_st + (size_t)w * HFO + lane * 4);
  float xsv[4] = {xs4.x, xs4.y, xs4.z, xs4.w};
  float xtv[4] = {xt4.x, xt4.y, xt4.z, xt4.w};
  float as[NC] = {}, at[NC] = {};
#pragma unroll
  for (int r = 0; r < 4; ++r) {
    int k = lane * 4 + r;
#pragma unroll
    for (int c = 0; c < NC; ++c) {
      as[c] = fmaf(xsv[r], WsL[k * NC + c], as[c]);
      at[c] = fmaf(xtv[r], WtL[k * NC + c], at[c]);
    }
  }
#pragma unroll
  for (int k = 1; k < 64; k <<= 1) {
#pragma unroll
    for (int c = 0; c < NC; ++c) {
      as[c] += __shfl_xor(as[c], k);
      at[c] += __shfl_xor(at[c], k);
    }
  }
  if (lane == 0) {
    float v1 = 0.f, v2 = 0.f, v3 = 0.f, v4 = 0.f;
#pragma unroll
    for (int c = 0; c < NC; ++c) {
      g_hs[w * NC + c] = as[c];
      g_ht[w * NC + c] = at[c];
      v1 = fmaf(as[c], a1o[c], v1);
      v2 = fmaf(at[c], a1o[NC + c], v2);
      v3 = fmaf(at[c], a2o[c], v3);
      v4 = fmaf(as[c], a2o[NC + c], v4);
    }
    gs1[w] = v1; gt1[w] = v2; gt2[w] = v3; gs2[w] = v4;
  }
}

// ---------------- layer-2 aggregation + ELU + log_softmax -> d_out -------------
__global__ __launch_bounds__(256) void agg2_kernel(
    const int* __restrict__ off, const int* __restrict__ idx,
    const int* __restrict__ other_end,
    const float* __restrict__ sA, const float* __restrict__ sB,
    const float* __restrict__ feat, float* __restrict__ out) {
  int w = (blockIdx.x * 256 + threadIdx.x) >> 6;
  int lane = threadIdx.x & 63;
  if (w >= GN) return;
  int beg = off[w];
  int d = off[w + 1] - beg;
  float sBn = sB[w];
  int c = lane & 7;
  float acc = 0.f;
  if (d > 0) {
    float m = -1e30f, sum = 0.f;
    for (int p = lane; p < d; p += 64) {
      int e = idx[beg + p]; int o = other_end[e];
      float x = sA[o] + sBn; x = x >= 0.f ? x : 0.1f * x;
      float nm = fmaxf(m, x);
      sum = sum * expf(m - nm) + expf(x - nm);
      m = nm;
    }
#pragma unroll
    for (int k = 1; k < 64; k <<= 1) {
      float om = __shfl_xor(m, k), os = __shfl_xor(sum, k);
      float nm = fmaxf(m, om);
      sum = sum * expf(m - nm) + os * expf(om - nm);
      m = nm;
    }
    float inv = 1.f / sum;
    for (int p = (lane >> 3); p < d; p += 8) {
      int e = idx[beg + p]; int o = other_end[e];
      float x = sA[o] + sBn; x = x >= 0.f ? x : 0.1f * x;
      acc = fmaf(expf(x - m) * inv, feat[o * NC + c], acc);
    }
#pragma unroll
    for (int k = 8; k < 64; k <<= 1) acc += __shfl_xor(acc, k);
  }
  acc = acc > 0.f ? acc : expf(acc) - 1.f;  // ELU
  float mx = acc;
#pragma unroll
  for (int k = 1; k < 8; k <<= 1) mx = fmaxf(mx, __shfl_xor(mx, k));
  float ex = expf(acc - mx);
  float se = ex;
#pragma unroll
  for (int k = 1; k < 8; k <<= 1) se += __shfl_xor(se, k);
  float r = acc - mx - logf(se);
  if (lane < NC) out[(size_t)w * NC + lane] = r;
}

extern "C" void kernel_launch(void* const* d_in, const int* in_sizes, int n_in,
                              void* d_out, int out_size, void* d_ws, size_t ws_size,
                              hipStream_t stream) {
  const float* x_source = (const float*)d_in[0];
  const float* x_target = (const float*)d_in[1];
  const int* edge_t = (const int*)d_in[2];
  const int* edge_s = (const int*)d_in[3];
  const float* Ws_h = (const float*)d_in[4];
  const float* Wt_h = (const float*)d_in[5];
  const float* a1_h = (const float*)d_in[6];
  const float* a2_h = (const float*)d_in[7];
  const float* Ws_o = (const float*)d_in[8];
  const float* Wt_o = (const float*)d_in[9];
  const float* a1_o = (const float*)d_in[10];
  const float* a2_o = (const float*)d_in[11];
  float* out = (float*)d_out;
  (void)in_sizes; (void)n_in; (void)out_size; (void)ws_size;

  char* wptr = (char*)d_ws;
  auto alloc = [&](size_t bytes) -> void* {
    void* p = (void*)wptr;
    wptr += (bytes + 255) & ~(size_t)255;
    return p;
  };
  float* hs_all = (float*)alloc((size_t)GN * HFO * 4);
  float* ht_all = (float*)alloc((size_t)GN * HFO * 4);
  float* out_ts = (float*)alloc((size_t)GN * HFO * 4);
  float* out_st = (float*)alloc((size_t)GN * HFO * 4);
  float* s1 = (float*)alloc((size_t)GN * NH * 4);
  float* t1 = (float*)alloc((size_t)GN * NH * 4);
  float* s2 = (float*)alloc((size_t)GN * NH * 4);
  float* t2 = (float*)alloc((size_t)GN * NH * 4);
  float* g_hs = (float*)alloc((size_t)GN * NC * 4);
  float* g_ht = (float*)alloc((size_t)GN * NC * 4);
  float* gs1 = (float*)alloc((size_t)GN * 4);
  float* gt1 = (float*)alloc((size_t)GN * 4);
  float* gt2 = (float*)alloc((size_t)GN * 4);
  float* gs2 = (float*)alloc((size_t)GN * 4);
  int* cnt_t = (int*)alloc((size_t)2 * GN * 4);  // cnt_t, cnt_s contiguous
  int* cnt_s = cnt_t + GN;
  int* off_t = (int*)alloc((size_t)(GN + 1) * 4);
  int* off_s = (int*)alloc((size_t)(GN + 1) * 4);
  int* cur_t = (int*)alloc((size_t)GN * 4);
  int* cur_s = (int*)alloc((size_t)GN * 4);
  int* idx_t = (int*)alloc((size_t)GE * 4);
  int* idx_s = (int*)alloc((size_t)GE * 4);

  hipMemsetAsync(cnt_t, 0, (size_t)2 * GN * 4, stream);

  gemm1_kernel<<<dim3(391, 2), 256, 0, stream>>>(x_source, Ws_h, hs_all);
  gemm1_kernel<<<dim3(391, 2), 256, 0, stream>>>(x_target, Wt_h, ht_all);
  node_scalar_kernel<<<12500, 256, 0, stream>>>(hs_all, ht_all, a1_h, a2_h, s1, t1, s2, t2);
  count_kernel<<<3125, 256, 0, stream>>>(edge_t, edge_s, cnt_t, cnt_s);
  scan_kernel<<<1, 1024, 0, stream>>>(cnt_t, off_t, cur_t);
  scan_kernel<<<1, 1024, 0, stream>>>(cnt_s, off_s, cur_s);
  scatter_kernel<<<3125, 256, 0, stream>>>(edge_t, edge_s, cur_t, cur_s, idx_t, idx_s);

  // layer 1: h_ts (segment by target, gather hs[source]); h_st (by source, gather ht[target])
  agg1_kernel<<<12500, 256, 0, stream>>>(off_t, idx_t, edge_s, s1, t1, hs_all, out_ts);
  agg1_kernel<<<12500, 256, 0, stream>>>(off_s, idx_s, edge_t, t2, s2, ht_all, out_st);

  gemm2_kernel<<<12500, 256, 0, stream>>>(out_ts, out_st, Ws_o, Wt_o, a1_o, a2_o,
                                          g_hs, g_ht, gs1, gt1, gt2, gs2);

  // layer 2: o_ts -> second half of d_out, o_st -> first half (return order: o_st, o_ts)
  agg2_kernel<<<12500, 256, 0, stream>>>(off_t, idx_t, edge_s, gs1, gt1, g_hs, out + (size_t)GN * NC);
  agg2_kernel<<<12500, 256, 0, stream>>>(off_s, idx_s, edge_t, gt2, gs2, g_ht, out);
}

// Round 2
// 775.036 us; speedup vs baseline: 1.3611x; 1.3611x over previous
//
#include <hip/hip_runtime.h>
#include <math.h>

#define GN 50000
#define GE 800000
#define DIN 128
#define FO 32
#define NH 8
#define HFO 256
#define NC 8
#define CAP 64

__device__ __forceinline__ void lds_fence() {
  asm volatile("s_waitcnt lgkmcnt(0)" ::: "memory");
  __builtin_amdgcn_sched_barrier(0);
}

// ---- GEMM1 (both inputs via blockIdx.z) + fused attention-scalar epilogue ----
__global__ __launch_bounds__(256) void gemm1_kernel(
    const float* __restrict__ x_source, const float* __restrict__ x_target,
    const float* __restrict__ Ws_h, const float* __restrict__ Wt_h,
    const float* __restrict__ a1_h, const float* __restrict__ a2_h,
    float* __restrict__ hs_all, float* __restrict__ ht_all,
    float* __restrict__ s1, float* __restrict__ t1,
    float* __restrict__ s2, float* __restrict__ t2) {
  __shared__ __align__(16) float As[32][132];
  __shared__ __align__(16) float Bs[32][128];
  const int z = blockIdx.z;
  const float* __restrict__ X = z ? x_target : x_source;
  const float* __restrict__ W = z ? Wt_h : Ws_h;
  float* __restrict__ outp = z ? ht_all : hs_all;
  float* __restrict__ sa_out = z ? t1 : s1;   // t1 = ht.a1[32:], s1 = hs.a1[:32]
  float* __restrict__ sb_out = z ? t2 : s2;   // t2 = ht.a2[:32], s2 = hs.a2[32:]
  const int offa = z ? FO : 0;
  const int offb = z ? 0 : FO;
  const int m0 = blockIdx.x * 128;
  const int c0 = blockIdx.y * 128;
  const int tid = threadIdx.x;
  const int ty = tid >> 4, tx = tid & 15;
  const int ry = ty * 8, cx = tx * 8;
  float acc[8][8] = {};
  for (int kb = 0; kb < 4; ++kb) {
    {
      int r = tid >> 3;
      int kk = (tid & 7) * 4;
#pragma unroll
      for (int p = 0; p < 4; ++p) {
        int row = r + p * 32;
        int grow = m0 + row; if (grow > GN - 1) grow = GN - 1;
        const float4 v = *reinterpret_cast<const float4*>(X + (size_t)grow * DIN + kb * 32 + kk);
        As[kk + 0][row] = v.x; As[kk + 1][row] = v.y;
        As[kk + 2][row] = v.z; As[kk + 3][row] = v.w;
      }
#pragma unroll
      for (int p = 0; p < 4; ++p) {
        int linear = (p * 256 + tid) * 4;
        int cc = linear & 127;
        int kl = linear >> 7;
        int c = c0 + cc;
        int h = c >> 5, f = c & 31;
        const float4 v = *reinterpret_cast<const float4*>(W + h * (DIN * FO) + (kb * 32 + kl) * FO + f);
        *reinterpret_cast<float4*>(&Bs[kl][cc]) = v;
      }
    }
    __syncthreads();
#pragma unroll
    for (int k = 0; k < 32; ++k) {
      float a[8], b[8];
      *reinterpret_cast<float4*>(&a[0]) = *reinterpret_cast<const float4*>(&As[k][ry]);
      *reinterpret_cast<float4*>(&a[4]) = *reinterpret_cast<const float4*>(&As[k][ry + 4]);
      *reinterpret_cast<float4*>(&b[0]) = *reinterpret_cast<const float4*>(&Bs[k][cx]);
      *reinterpret_cast<float4*>(&b[4]) = *reinterpret_cast<const float4*>(&Bs[k][cx + 4]);
#pragma unroll
      for (int i = 0; i < 8; ++i)
#pragma unroll
        for (int j = 0; j < 8; ++j)
          acc[i][j] = fmaf(a[i], b[j], acc[i][j]);
    }
    __syncthreads();
  }
  // store output tile
#pragma unroll
  for (int i = 0; i < 8; ++i) {
    int row = m0 + ry + i;
    if (row < GN) {
      float4 v0 = make_float4(acc[i][0], acc[i][1], acc[i][2], acc[i][3]);
      float4 v1 = make_float4(acc[i][4], acc[i][5], acc[i][6], acc[i][7]);
      float* p = outp + (size_t)row * HFO + c0 + cx;
      *reinterpret_cast<float4*>(p) = v0;
      *reinterpret_cast<float4*>(p + 4) = v1;
    }
  }
  // fused per-node attention scalars: this thread's 8 cols lie in one head
  const int head = (c0 >> 5) + (tx >> 2);
  const int fbase = (tx & 3) * 8;
  float av[8], bv[8];
#pragma unroll
  for (int jj = 0; jj < 8; ++jj) {
    av[jj] = a1_h[head * 64 + offa + fbase + jj];
    bv[jj] = a2_h[head * 64 + offb + fbase + jj];
  }
#pragma unroll
  for (int i = 0; i < 8; ++i) {
    float da = 0.f, db = 0.f;
#pragma unroll
    for (int jj = 0; jj < 8; ++jj) {
      da = fmaf(acc[i][jj], av[jj], da);
      db = fmaf(acc[i][jj], bv[jj], db);
    }
    da += __shfl_xor(da, 1); da += __shfl_xor(da, 2);
    db += __shfl_xor(db, 1); db += __shfl_xor(db, 2);
    int row = m0 + ry + i;
    if ((tx & 3) == 0 && row < GN) {
      sa_out[row * NH + head] = da;
      sb_out[row * NH + head] = db;
    }
  }
}

// ---------------- CSR build ----------------
__global__ __launch_bounds__(256) void count_kernel(const int* __restrict__ et,
                                                    const int* __restrict__ es,
                                                    int* cnt_t, int* cnt_s) {
  int e4 = blockIdx.x * 256 + threadIdx.x;
  if (e4 < GE / 4) {
    int4 t4 = reinterpret_cast<const int4*>(et)[e4];
    int4 s4 = reinterpret_cast<const int4*>(es)[e4];
    atomicAdd(&cnt_t[t4.x], 1); atomicAdd(&cnt_t[t4.y], 1);
    atomicAdd(&cnt_t[t4.z], 1); atomicAdd(&cnt_t[t4.w], 1);
    atomicAdd(&cnt_s[s4.x], 1); atomicAdd(&cnt_s[s4.y], 1);
    atomicAdd(&cnt_s[s4.z], 1); atomicAdd(&cnt_s[s4.w], 1);
  }
}

__global__ __launch_bounds__(1024) void scan_kernel(
    const int* __restrict__ cnt_t, int* __restrict__ off_t, int* __restrict__ cur_t,
    const int* __restrict__ cnt_s, int* __restrict__ off_s, int* __restrict__ cur_s) {
  const int* cnt = blockIdx.x ? cnt_s : cnt_t;
  int* off = blockIdx.x ? off_s : off_t;
  int* cur = blockIdx.x ? cur_s : cur_t;
  __shared__ int part[1024];
  const int SEG = (GN + 1023) / 1024;  // 49
  int t = threadIdx.x;
  int start = t * SEG;
  int end = start + SEG; if (end > GN) end = GN;
  int s = 0;
  for (int i = start; i < end; ++i) s += cnt[i];
  part[t] = s;
  __syncthreads();
  for (int dstep = 1; dstep < 1024; dstep <<= 1) {
    int v = part[t];
    int u = (t >= dstep) ? part[t - dstep] : 0;
    __syncthreads();
    part[t] = v + u;
    __syncthreads();
  }
  int run = (t == 0) ? 0 : part[t - 1];
  for (int i = start; i < end; ++i) { off[i] = run; cur[i] = run; run += cnt[i]; }
  if (t == 1023) off[GN] = part[1023];
}

__global__ __launch_bounds__(256) void scatter_kernel(const int* __restrict__ et,
                                                      const int* __restrict__ es,
                                                      int* cur_t, int* cur_s,
                                                      int* adj_t, int* adj_s) {
  int e4 = blockIdx.x * 256 + threadIdx.x;
  if (e4 < GE / 4) {
    int4 t4 = reinterpret_cast<const int4*>(et)[e4];
    int4 s4 = reinterpret_cast<const int4*>(es)[e4];
    adj_t[atomicAdd(&cur_t[t4.x], 1)] = s4.x;
    adj_t[atomicAdd(&cur_t[t4.y], 1)] = s4.y;
    adj_t[atomicAdd(&cur_t[t4.z], 1)] = s4.z;
    adj_t[atomicAdd(&cur_t[t4.w], 1)] = s4.w;
    adj_s[atomicAdd(&cur_s[s4.x], 1)] = t4.x;
    adj_s[atomicAdd(&cur_s[s4.y], 1)] = t4.y;
    adj_s[atomicAdd(&cur_s[s4.z], 1)] = t4.z;
    adj_s[atomicAdd(&cur_s[s4.w], 1)] = t4.w;
  }
}

// ---- layer-1 aggregation, both directions in one launch, LDS weight cache ----
__global__ __launch_bounds__(256) void agg1_kernel(
    const int* __restrict__ off_t, const int* __restrict__ adj_t,
    const float* __restrict__ s1, const float* __restrict__ t1, const float* __restrict__ hs,
    const int* __restrict__ off_s, const int* __restrict__ adj_s,
    const float* __restrict__ t2, const float* __restrict__ s2, const float* __restrict__ ht,
    float* __restrict__ out_ts, float* __restrict__ out_st) {
  __shared__ int s_o[4][CAP];
  __shared__ float s_x[4][CAP][NH];
  const int wv = threadIdx.x >> 6;
  const int lane = threadIdx.x & 63;
  const int gw = blockIdx.x * 4 + wv;
  const bool dir = gw >= GN;
  const int w = dir ? gw - GN : gw;
  const int* __restrict__ off = dir ? off_s : off_t;
  const int* __restrict__ adj = dir ? adj_s : adj_t;
  const float* __restrict__ sA = dir ? t2 : s1;
  const float* __restrict__ sB = dir ? s2 : t1;
  const float* __restrict__ feat = dir ? ht : hs;
  float* __restrict__ out = dir ? out_st : out_ts;

  const int beg = off[w];
  const int d = off[w + 1] - beg;
  const int h = lane >> 3;
  const int j = lane & 7;
  float acc0 = 0.f, acc1 = 0.f, acc2 = 0.f, acc3 = 0.f;
  if (d > 0) {
    const float sBn = sB[w * NH + h];
    // pass 1: logits -> LDS, running max
    float m = -1e30f;
    for (int p = j; p < d; p += 8) {
      int o = adj[beg + p];
      float x = sA[o * NH + h] + sBn;
      x = x >= 0.f ? x : 0.1f * x;
      if (p < CAP) { if (h == 0) s_o[wv][p] = o; s_x[wv][p][h] = x; }
      m = fmaxf(m, x);
    }
#pragma unroll
    for (int k = 1; k < 8; k <<= 1) m = fmaxf(m, __shfl_xor(m, k));
    lds_fence();
    // pass 2: e = exp(x-m), store back, sum
    const int dc = d < CAP ? d : CAP;
    float sum = 0.f;
    for (int p = j; p < dc; p += 8) {
      float e = __expf(s_x[wv][p][h] - m);
      s_x[wv][p][h] = e;
      sum += e;
    }
    for (int p = CAP + j; p < d; p += 8) {  // overflow (practically never)
      int o = adj[beg + p];
      float x = sA[o * NH + h] + sBn;
      x = x >= 0.f ? x : 0.1f * x;
      sum += __expf(x - m);
    }
#pragma unroll
    for (int k = 1; k < 8; k <<= 1) sum += __shfl_xor(sum, k);
    float inv = 1.f / sum;
    lds_fence();
    // phase B: gather feature rows, 4-wide
    const float* __restrict__ featl = feat + lane * 4;
    int p = 0;
    for (; p + 4 <= dc; p += 4) {
      int4 oo = *reinterpret_cast<const int4*>(&s_o[wv][p]);
      float w0 = s_x[wv][p + 0][h];
      float w1 = s_x[wv][p + 1][h];
      float w2 = s_x[wv][p + 2][h];
      float w3 = s_x[wv][p + 3][h];
      float4 v0 = *reinterpret_cast<const float4*>(featl + (size_t)oo.x * HFO);
      float4 v1 = *reinterpret_cast<const float4*>(featl + (size_t)oo.y * HFO);
      float4 v2 = *reinterpret_cast<const float4*>(featl + (size_t)oo.z * HFO);
      float4 v3 = *reinterpret_cast<const float4*>(featl + (size_t)oo.w * HFO);
      acc0 = fmaf(w0, v0.x, acc0); acc1 = fmaf(w0, v0.y, acc1);
      acc2 = fmaf(w0, v0.z, acc2); acc3 = fmaf(w0, v0.w, acc3);
      acc0 = fmaf(w1, v1.x, acc0); acc1 = fmaf(w1, v1.y, acc1);
      acc2 = fmaf(w1, v1.z, acc2); acc3 = fmaf(w1, v1.w, acc3);
      acc0 = fmaf(w2, v2.x, acc0); acc1 = fmaf(w2, v2.y, acc1);
      acc2 = fmaf(w2, v2.z, acc2); acc3 = fmaf(w2, v2.w, acc3);
      acc0 = fmaf(w3, v3.x, acc0); acc1 = fmaf(w3, v3.y, acc1);
      acc2 = fmaf(w3, v3.z, acc2); acc3 = fmaf(w3, v3.w, acc3);
    }
    for (; p < dc; ++p) {
      int o = s_o[wv][p];
      float wg = s_x[wv][p][h];
      float4 v = *reinterpret_cast<const float4*>(featl + (size_t)o * HFO);
      acc0 = fmaf(wg, v.x, acc0); acc1 = fmaf(wg, v.y, acc1);
      acc2 = fmaf(wg, v.z, acc2); acc3 = fmaf(wg, v.w, acc3);
    }
    for (; p < d; ++p) {  // overflow
      int o = adj[beg + p];
      float x = sA[o * NH + h] + sBn;
      x = x >= 0.f ? x : 0.1f * x;
      float wg = __expf(x - m);
      float4 v = *reinterpret_cast<const float4*>(featl + (size_t)o * HFO);
      acc0 = fmaf(wg, v.x, acc0); acc1 = fmaf(wg, v.y, acc1);
      acc2 = fmaf(wg, v.z, acc2); acc3 = fmaf(wg, v.w, acc3);
    }
    acc0 *= inv; acc1 *= inv; acc2 *= inv; acc3 *= inv;
  }
  float4 r;  // ELU
  r.x = acc0 > 0.f ? acc0 : __expf(acc0) - 1.f;
  r.y = acc1 > 0.f ? acc1 : __expf(acc1) - 1.f;
  r.z = acc2 > 0.f ? acc2 : __expf(acc2) - 1.f;
  r.w = acc3 > 0.f ? acc3 : __expf(acc3) - 1.f;
  *reinterpret_cast<float4*>(out + (size_t)w * HFO + lane * 4) = r;
}

// ---------------- layer-2 projection + logit scalars (one wave per node) -------
__global__ __launch_bounds__(256) void gemm2_kernel(
    const float* __restrict__ out_ts, const float* __restrict__ out_st,
    const float* __restrict__ Wso, const float* __restrict__ Wto,
    const float* __restrict__ a1o, const float* __restrict__ a2o,
    float* __restrict__ g_hs, float* __restrict__ g_ht,
    float* __restrict__ gs1, float* __restrict__ gt1,
    float* __restrict__ gt2, float* __restrict__ gs2) {
  __shared__ float WsL[HFO * NC], WtL[HFO * NC];
  for (int i = threadIdx.x; i < HFO * NC; i += 256) { WsL[i] = Wso[i]; WtL[i] = Wto[i]; }
  __syncthreads();
  int w = (blockIdx.x * 256 + threadIdx.x) >> 6;
  int lane = threadIdx.x & 63;
  if (w >= GN) return;
  float4 xs4 = *reinterpret_cast<const float4*>(out_ts + (size_t)w * HFO + lane * 4);
  float4 xt4 = *reinterpret_cast<const float4*>(out_st + (size_t)w * HFO + lane * 4);
  float xsv[4] = {xs4.x, xs4.y, xs4.z, xs4.w};
  float xtv[4] = {xt4.x, xt4.y, xt4.z, xt4.w};
  float as[NC] = {}, at[NC] = {};
#pragma unroll
  for (int r = 0; r < 4; ++r) {
    int k = lane * 4 + r;
#pragma unroll
    for (int c = 0; c < NC; ++c) {
      as[c] = fmaf(xsv[r], WsL[k * NC + c], as[c]);
      at[c] = fmaf(xtv[r], WtL[k * NC + c], at[c]);
    }
  }
#pragma unroll
  for (int k = 1; k < 64; k <<= 1) {
#pragma unroll
    for (int c = 0; c < NC; ++c) {
      as[c] += __shfl_xor(as[c], k);
      at[c] += __shfl_xor(at[c], k);
    }
  }
  if (lane == 0) {
    float v1 = 0.f, v2 = 0.f, v3 = 0.f, v4 = 0.f;
#pragma unroll
    for (int c = 0; c < NC; ++c) {
      g_hs[w * NC + c] = as[c];
      g_ht[w * NC + c] = at[c];
      v1 = fmaf(as[c], a1o[c], v1);
      v2 = fmaf(at[c], a1o[NC + c], v2);
      v3 = fmaf(at[c], a2o[c], v3);
      v4 = fmaf(as[c], a2o[NC + c], v4);
    }
    gs1[w] = v1; gt1[w] = v2; gt2[w] = v3; gs2[w] = v4;
  }
}

// ---- layer-2 aggregation + ELU + log_softmax, both directions in one launch ----
__global__ __launch_bounds__(256) void agg2_kernel(
    const int* __restrict__ off_t, const int* __restrict__ adj_t,
    const float* __restrict__ gs1, const float* __restrict__ gt1, const float* __restrict__ g_hs,
    const int* __restrict__ off_s, const int* __restrict__ adj_s,
    const float* __restrict__ gt2, const float* __restrict__ gs2, const float* __restrict__ g_ht,
    float* __restrict__ d_out) {
  __shared__ int s_o[4][CAP];
  __shared__ float s_w[4][CAP];
  const int wv = threadIdx.x >> 6;
  const int lane = threadIdx.x & 63;
  const int gw = blockIdx.x * 4 + wv;
  const bool dir = gw >= GN;
  const int w = dir ? gw - GN : gw;
  const int* __restrict__ off = dir ? off_s : off_t;
  const int* __restrict__ adj = dir ? adj_s : adj_t;
  const float* __restrict__ sA = dir ? gt2 : gs1;
  const float* __restrict__ sB = dir ? gs2 : gt1;
  const float* __restrict__ feat = dir ? g_ht : g_hs;
  float* __restrict__ out = dir ? d_out : d_out + (size_t)GN * NC;

  const int beg = off[w];
  const int d = off[w + 1] - beg;
  const int c = lane & 7;
  const int g = lane >> 3;
  float acc = 0.f;
  if (d > 0) {
    const float sBn = sB[w];
    float m = -1e30f;
    for (int p = lane; p < d; p += 64) {
      int o = adj[beg + p];
      float x = sA[o] + sBn;
      x = x >= 0.f ? x : 0.1f * x;
      if (p < CAP) { s_o[wv][p] = o; s_w[wv][p] = x; }
      m = fmaxf(m, x);
    }
#pragma unroll
    for (int k = 1; k < 64; k <<= 1) m = fmaxf(m, __shfl_xor(m, k));
    lds_fence();
    const int dc = d < CAP ? d : CAP;
    float sum = 0.f;
    for (int p = lane; p < dc; p += 64) {
      float e = __expf(s_w[wv][p] - m);
      s_w[wv][p] = e;
      sum += e;
    }
    for (int p = CAP + lane; p < d; p += 64) {
      int o = adj[beg + p];
      float x = sA[o] + sBn;
      x = x >= 0.f ? x : 0.1f * x;
      sum += __expf(x - m);
    }
#pragma unroll
    for (int k = 1; k < 64; k <<= 1) sum += __shfl_xor(sum, k);
    float inv = 1.f / sum;
    lds_fence();
    for (int p = g; p < dc; p += 8)
      acc = fmaf(s_w[wv][p], feat[(size_t)s_o[wv][p] * NC + c], acc);
    for (int p = dc + g; p < d; p += 8) {  // overflow
      int o = adj[beg + p];
      float x = sA[o] + sBn;
      x = x >= 0.f ? x : 0.1f * x;
      acc = fmaf(__expf(x - m), feat[(size_t)o * NC + c], acc);
    }
#pragma unroll
    for (int k = 8; k < 64; k <<= 1) acc += __shfl_xor(acc, k);
    acc *= inv;
  }
  acc = acc > 0.f ? acc : __expf(acc) - 1.f;  // ELU
  float mx = acc;
#pragma unroll
  for (int k = 1; k < 8; k <<= 1) mx = fmaxf(mx, __shfl_xor(mx, k));
  float ex = __expf(acc - mx);
  float se = ex;
#pragma unroll
  for (int k = 1; k < 8; k <<= 1) se += __shfl_xor(se, k);
  float r = acc - mx - logf(se);
  if (lane < NC) out[(size_t)w * NC + lane] = r;
}

extern "C" void kernel_launch(void* const* d_in, const int* in_sizes, int n_in,
                              void* d_out, int out_size, void* d_ws, size_t ws_size,
                              hipStream_t stream) {
  const float* x_source = (const float*)d_in[0];
  const float* x_target = (const float*)d_in[1];
  const int* edge_t = (const int*)d_in[2];
  const int* edge_s = (const int*)d_in[3];
  const float* Ws_h = (const float*)d_in[4];
  const float* Wt_h = (const float*)d_in[5];
  const float* a1_h = (const float*)d_in[6];
  const float* a2_h = (const float*)d_in[7];
  const float* Ws_o = (const float*)d_in[8];
  const float* Wt_o = (const float*)d_in[9];
  const float* a1_o = (const float*)d_in[10];
  const float* a2_o = (const float*)d_in[11];
  float* out = (float*)d_out;
  (void)in_sizes; (void)n_in; (void)out_size; (void)ws_size;

  char* wptr = (char*)d_ws;
  auto alloc = [&](size_t bytes) -> void* {
    void* p = (void*)wptr;
    wptr += (bytes + 255) & ~(size_t)255;
    return p;
  };
  float* hs_all = (float*)alloc((size_t)GN * HFO * 4);
  float* ht_all = (float*)alloc((size_t)GN * HFO * 4);
  float* out_ts = (float*)alloc((size_t)GN * HFO * 4);
  float* out_st = (float*)alloc((size_t)GN * HFO * 4);
  float* s1 = (float*)alloc((size_t)GN * NH * 4);
  float* t1 = (float*)alloc((size_t)GN * NH * 4);
  float* s2 = (float*)alloc((size_t)GN * NH * 4);
  float* t2 = (float*)alloc((size_t)GN * NH * 4);
  float* g_hs = (float*)alloc((size_t)GN * NC * 4);
  float* g_ht = (float*)alloc((size_t)GN * NC * 4);
  float* gs1 = (float*)alloc((size_t)GN * 4);
  float* gt1 = (float*)alloc((size_t)GN * 4);
  float* gt2 = (float*)alloc((size_t)GN * 4);
  float* gs2 = (float*)alloc((size_t)GN * 4);
  int* cnt_t = (int*)alloc((size_t)2 * GN * 4);
  int* cnt_s = cnt_t + GN;
  int* off_t = (int*)alloc((size_t)(GN + 1) * 4);
  int* off_s = (int*)alloc((size_t)(GN + 1) * 4);
  int* cur_t = (int*)alloc((size_t)GN * 4);
  int* cur_s = (int*)alloc((size_t)GN * 4);
  int* adj_t = (int*)alloc((size_t)GE * 4);
  int* adj_s = (int*)alloc((size_t)GE * 4);

  hipMemsetAsync(cnt_t, 0, (size_t)2 * GN * 4, stream);

  gemm1_kernel<<<dim3(391, 2, 2), 256, 0, stream>>>(
      x_source, x_target, Ws_h, Wt_h, a1_h, a2_h,
      hs_all, ht_all, s1, t1, s2, t2);
  count_kernel<<<782, 256, 0, stream>>>(edge_t, edge_s, cnt_t, cnt_s);
  scan_kernel<<<2, 1024, 0, stream>>>(cnt_t, off_t, cur_t, cnt_s, off_s, cur_s);
  scatter_kernel<<<782, 256, 0, stream>>>(edge_t, edge_s, cur_t, cur_s, adj_t, adj_s);

  agg1_kernel<<<25000, 256, 0, stream>>>(off_t, adj_t, s1, t1, hs_all,
                                         off_s, adj_s, t2, s2, ht_all,
                                         out_ts, out_st);
  gemm2_kernel<<<12500, 256, 0, stream>>>(out_ts, out_st, Ws_o, Wt_o, a1_o, a2_o,
                                          g_hs, g_ht, gs1, gt1, gt2, gs2);
  agg2_kernel<<<25000, 256, 0, stream>>>(off_t, adj_t, gs1, gt1, g_hs,
                                         off_s, adj_s, gt2, gs2, g_ht, out);
}

// Round 3
// 593.866 us; speedup vs baseline: 1.7763x; 1.3051x over previous
//
#include <hip/hip_runtime.h>
#include <math.h>

#define GN 50000
#define GE 800000
#define DIN 128
#define FO 32
#define NH 8
#define HFO 256
#define NC 8
#define CAP 64

__device__ __forceinline__ void lds_fence() {
  asm volatile("s_waitcnt lgkmcnt(0)" ::: "memory");
  __builtin_amdgcn_sched_barrier(0);
}

__device__ __forceinline__ ushort f2bf(float f) {
  uint x = __float_as_uint(f);
  return (ushort)((x + 0x7fffu + ((x >> 16) & 1u)) >> 16);
}
__device__ __forceinline__ float bf2f(ushort u) {
  return __uint_as_float(((uint)u) << 16);
}

// ---- GEMM1 (both inputs via blockIdx.z), bf16 feature output + fused scalars ----
__global__ __launch_bounds__(256) void gemm1_kernel(
    const float* __restrict__ x_source, const float* __restrict__ x_target,
    const float* __restrict__ Ws_h, const float* __restrict__ Wt_h,
    const float* __restrict__ a1_h, const float* __restrict__ a2_h,
    ushort* __restrict__ hs16, ushort* __restrict__ ht16,
    float* __restrict__ s1, float* __restrict__ t1,
    float* __restrict__ s2, float* __restrict__ t2) {
  __shared__ __align__(16) float As[32][132];
  __shared__ __align__(16) float Bs[32][128];
  const int z = blockIdx.z;
  const float* __restrict__ X = z ? x_target : x_source;
  const float* __restrict__ W = z ? Wt_h : Ws_h;
  ushort* __restrict__ outp = z ? ht16 : hs16;
  float* __restrict__ sa_out = z ? t1 : s1;   // t1 = ht.a1[32:], s1 = hs.a1[:32]
  float* __restrict__ sb_out = z ? t2 : s2;   // t2 = ht.a2[:32], s2 = hs.a2[32:]
  const int offa = z ? FO : 0;
  const int offb = z ? 0 : FO;
  const int m0 = blockIdx.x * 128;
  const int c0 = blockIdx.y * 128;
  const int tid = threadIdx.x;
  const int ty = tid >> 4, tx = tid & 15;
  const int ry = ty * 8, cx = tx * 8;
  float acc[8][8] = {};
  for (int kb = 0; kb < 4; ++kb) {
    {
      int r = tid >> 3;
      int kk = (tid & 7) * 4;
#pragma unroll
      for (int p = 0; p < 4; ++p) {
        int row = r + p * 32;
        int grow = m0 + row; if (grow > GN - 1) grow = GN - 1;
        const float4 v = *reinterpret_cast<const float4*>(X + (size_t)grow * DIN + kb * 32 + kk);
        As[kk + 0][row] = v.x; As[kk + 1][row] = v.y;
        As[kk + 2][row] = v.z; As[kk + 3][row] = v.w;
      }
#pragma unroll
      for (int p = 0; p < 4; ++p) {
        int linear = (p * 256 + tid) * 4;
        int cc = linear & 127;
        int kl = linear >> 7;
        int c = c0 + cc;
        int h = c >> 5, f = c & 31;
        const float4 v = *reinterpret_cast<const float4*>(W + h * (DIN * FO) + (kb * 32 + kl) * FO + f);
        *reinterpret_cast<float4*>(&Bs[kl][cc]) = v;
      }
    }
    __syncthreads();
#pragma unroll
    for (int k = 0; k < 32; ++k) {
      float a[8], b[8];
      *reinterpret_cast<float4*>(&a[0]) = *reinterpret_cast<const float4*>(&As[k][ry]);
      *reinterpret_cast<float4*>(&a[4]) = *reinterpret_cast<const float4*>(&As[k][ry + 4]);
      *reinterpret_cast<float4*>(&b[0]) = *reinterpret_cast<const float4*>(&Bs[k][cx]);
      *reinterpret_cast<float4*>(&b[4]) = *reinterpret_cast<const float4*>(&Bs[k][cx + 4]);
#pragma unroll
      for (int i = 0; i < 8; ++i)
#pragma unroll
        for (int j = 0; j < 8; ++j)
          acc[i][j] = fmaf(a[i], b[j], acc[i][j]);
    }
    __syncthreads();
  }
  // store bf16 feature tile
#pragma unroll
  for (int i = 0; i < 8; ++i) {
    int row = m0 + ry + i;
    if (row < GN) {
      union { ushort u[8]; uint4 q; } pk;
#pragma unroll
      for (int jj = 0; jj < 8; ++jj) pk.u[jj] = f2bf(acc[i][jj]);
      *reinterpret_cast<uint4*>(outp + (size_t)row * HFO + c0 + cx) = pk.q;
    }
  }
  // fused per-node attention scalars (f32, from f32 accumulators)
  const int head = (c0 >> 5) + (tx >> 2);
  const int fbase = (tx & 3) * 8;
  float av[8], bv[8];
#pragma unroll
  for (int jj = 0; jj < 8; ++jj) {
    av[jj] = a1_h[head * 64 + offa + fbase + jj];
    bv[jj] = a2_h[head * 64 + offb + fbase + jj];
  }
#pragma unroll
  for (int i = 0; i < 8; ++i) {
    float da = 0.f, db = 0.f;
#pragma unroll
    for (int jj = 0; jj < 8; ++jj) {
      da = fmaf(acc[i][jj], av[jj], da);
      db = fmaf(acc[i][jj], bv[jj], db);
    }
    da += __shfl_xor(da, 1); da += __shfl_xor(da, 2);
    db += __shfl_xor(db, 1); db += __shfl_xor(db, 2);
    int row = m0 + ry + i;
    if ((tx & 3) == 0 && row < GN) {
      sa_out[row * NH + head] = da;
      sb_out[row * NH + head] = db;
    }
  }
}

// ---------------- CSR build ----------------
__global__ __launch_bounds__(256) void count_kernel(const int* __restrict__ et,
                                                    const int* __restrict__ es,
                                                    int* cnt_t, int* cnt_s) {
  int e4 = blockIdx.x * 256 + threadIdx.x;
  if (e4 < GE / 4) {
    int4 t4 = reinterpret_cast<const int4*>(et)[e4];
    int4 s4 = reinterpret_cast<const int4*>(es)[e4];
    atomicAdd(&cnt_t[t4.x], 1); atomicAdd(&cnt_t[t4.y], 1);
    atomicAdd(&cnt_t[t4.z], 1); atomicAdd(&cnt_t[t4.w], 1);
    atomicAdd(&cnt_s[s4.x], 1); atomicAdd(&cnt_s[s4.y], 1);
    atomicAdd(&cnt_s[s4.z], 1); atomicAdd(&cnt_s[s4.w], 1);
  }
}

__global__ __launch_bounds__(1024) void scan_kernel(
    const int* __restrict__ cnt_t, int* __restrict__ off_t, int* __restrict__ cur_t,
    const int* __restrict__ cnt_s, int* __restrict__ off_s, int* __restrict__ cur_s) {
  const int* cnt = blockIdx.x ? cnt_s : cnt_t;
  int* off = blockIdx.x ? off_s : off_t;
  int* cur = blockIdx.x ? cur_s : cur_t;
  __shared__ int part[1024];
  const int SEG = (GN + 1023) / 1024;  // 49
  int t = threadIdx.x;
  int start = t * SEG;
  int end = start + SEG; if (end > GN) end = GN;
  int s = 0;
  for (int i = start; i < end; ++i) s += cnt[i];
  part[t] = s;
  __syncthreads();
  for (int dstep = 1; dstep < 1024; dstep <<= 1) {
    int v = part[t];
    int u = (t >= dstep) ? part[t - dstep] : 0;
    __syncthreads();
    part[t] = v + u;
    __syncthreads();
  }
  int run = (t == 0) ? 0 : part[t - 1];
  for (int i = start; i < end; ++i) { off[i] = run; cur[i] = run; run += cnt[i]; }
  if (t == 1023) off[GN] = part[1023];
}

__global__ __launch_bounds__(256) void scatter_kernel(const int* __restrict__ et,
                                                      const int* __restrict__ es,
                                                      int* cur_t, int* cur_s,
                                                      int* adj_t, int* adj_s) {
  int e4 = blockIdx.x * 256 + threadIdx.x;
  if (e4 < GE / 4) {
    int4 t4 = reinterpret_cast<const int4*>(et)[e4];
    int4 s4 = reinterpret_cast<const int4*>(es)[e4];
    adj_t[atomicAdd(&cur_t[t4.x], 1)] = s4.x;
    adj_t[atomicAdd(&cur_t[t4.y], 1)] = s4.y;
    adj_t[atomicAdd(&cur_t[t4.z], 1)] = s4.z;
    adj_t[atomicAdd(&cur_t[t4.w], 1)] = s4.w;
    adj_s[atomicAdd(&cur_s[s4.x], 1)] = t4.x;
    adj_s[atomicAdd(&cur_s[s4.y], 1)] = t4.y;
    adj_s[atomicAdd(&cur_s[s4.z], 1)] = t4.z;
    adj_s[atomicAdd(&cur_s[s4.w], 1)] = t4.w;
  }
}

// ---- one direction of layer-1 aggregation for node w (per-wave) -------------
__device__ __forceinline__ float4 agg_dir(
    const int* __restrict__ off, const int* __restrict__ adj,
    const float* __restrict__ sA, const float* __restrict__ sB,
    const ushort* __restrict__ feat,
    int w, int h, int j, int lane,
    int* __restrict__ s_o_w, float* __restrict__ s_x_w) {
  const int beg = off[w];
  const int d = off[w + 1] - beg;
  float acc0 = 0.f, acc1 = 0.f, acc2 = 0.f, acc3 = 0.f;
  float inv = 0.f;
  if (d > 0) {
    const float sBn = sB[w * NH + h];
    float m = -1e30f;
    for (int p = j; p < d; p += 8) {
      int o = adj[beg + p];
      float x = sA[o * NH + h] + sBn;
      x = x >= 0.f ? x : 0.1f * x;
      if (p < CAP) { if (h == 0) s_o_w[p] = o; s_x_w[p * NH + h] = x; }
      m = fmaxf(m, x);
    }
#pragma unroll
    for (int k = 1; k < 8; k <<= 1) m = fmaxf(m, __shfl_xor(m, k));
    lds_fence();
    const int dc = d < CAP ? d : CAP;
    float sum = 0.f;
    for (int p = j; p < dc; p += 8) {
      float e = __expf(s_x_w[p * NH + h] - m);
      s_x_w[p * NH + h] = e;
      sum += e;
    }
    for (int p = CAP + j; p < d; p += 8) {  // overflow (practically never)
      int o = adj[beg + p];
      float x = sA[o * NH + h] + sBn;
      x = x >= 0.f ? x : 0.1f * x;
      sum += __expf(x - m);
    }
#pragma unroll
    for (int k = 1; k < 8; k <<= 1) sum += __shfl_xor(sum, k);
    inv = 1.f / sum;
    lds_fence();
    const ushort* __restrict__ featl = feat + lane * 4;
    int p = 0;
    for (; p + 4 <= dc; p += 4) {
      int4 oo = *reinterpret_cast<const int4*>(&s_o_w[p]);
      float w0 = s_x_w[(p + 0) * NH + h];
      float w1 = s_x_w[(p + 1) * NH + h];
      float w2 = s_x_w[(p + 2) * NH + h];
      float w3 = s_x_w[(p + 3) * NH + h];
      ushort4 v0 = *reinterpret_cast<const ushort4*>(featl + (size_t)oo.x * HFO);
      ushort4 v1 = *reinterpret_cast<const ushort4*>(featl + (size_t)oo.y * HFO);
      ushort4 v2 = *reinterpret_cast<const ushort4*>(featl + (size_t)oo.z * HFO);
      ushort4 v3 = *reinterpret_cast<const ushort4*>(featl + (size_t)oo.w * HFO);
      acc0 = fmaf(w0, bf2f(v0.x), acc0); acc1 = fmaf(w0, bf2f(v0.y), acc1);
      acc2 = fmaf(w0, bf2f(v0.z), acc2); acc3 = fmaf(w0, bf2f(v0.w), acc3);
      acc0 = fmaf(w1, bf2f(v1.x), acc0); acc1 = fmaf(w1, bf2f(v1.y), acc1);
      acc2 = fmaf(w1, bf2f(v1.z), acc2); acc3 = fmaf(w1, bf2f(v1.w), acc3);
      acc0 = fmaf(w2, bf2f(v2.x), acc0); acc1 = fmaf(w2, bf2f(v2.y), acc1);
      acc2 = fmaf(w2, bf2f(v2.z), acc2); acc3 = fmaf(w2, bf2f(v2.w), acc3);
      acc0 = fmaf(w3, bf2f(v3.x), acc0); acc1 = fmaf(w3, bf2f(v3.y), acc1);
      acc2 = fmaf(w3, bf2f(v3.z), acc2); acc3 = fmaf(w3, bf2f(v3.w), acc3);
    }
    for (; p < dc; ++p) {
      int o = s_o_w[p];
      float wg = s_x_w[p * NH + h];
      ushort4 v = *reinterpret_cast<const ushort4*>(featl + (size_t)o * HFO);
      acc0 = fmaf(wg, bf2f(v.x), acc0); acc1 = fmaf(wg, bf2f(v.y), acc1);
      acc2 = fmaf(wg, bf2f(v.z), acc2); acc3 = fmaf(wg, bf2f(v.w), acc3);
    }
    for (; p < d; ++p) {  // overflow
      int o = adj[beg + p];
      float x = sA[o * NH + h] + sBn;
      x = x >= 0.f ? x : 0.1f * x;
      float wg = __expf(x - m);
      ushort4 v = *reinterpret_cast<const ushort4*>(featl + (size_t)o * HFO);
      acc0 = fmaf(wg, bf2f(v.x), acc0); acc1 = fmaf(wg, bf2f(v.y), acc1);
      acc2 = fmaf(wg, bf2f(v.z), acc2); acc3 = fmaf(wg, bf2f(v.w), acc3);
    }
    acc0 *= inv; acc1 *= inv; acc2 *= inv; acc3 *= inv;
  }
  float4 r;  // ELU (concat=True)
  r.x = acc0 > 0.f ? acc0 : __expf(acc0) - 1.f;
  r.y = acc1 > 0.f ? acc1 : __expf(acc1) - 1.f;
  r.z = acc2 > 0.f ? acc2 : __expf(acc2) - 1.f;
  r.w = acc3 > 0.f ? acc3 : __expf(acc3) - 1.f;
  return r;
}

// ---- layer-1 aggregation (both dirs per wave) + fused layer-2 projection -----
__global__ __launch_bounds__(256) void agg1_kernel(
    const int* __restrict__ off_t, const int* __restrict__ adj_t,
    const float* __restrict__ s1, const float* __restrict__ t1,
    const int* __restrict__ off_s, const int* __restrict__ adj_s,
    const float* __restrict__ t2, const float* __restrict__ s2,
    const ushort* __restrict__ hs16, const ushort* __restrict__ ht16,
    const float* __restrict__ Wso, const float* __restrict__ Wto,
    const float* __restrict__ a1o, const float* __restrict__ a2o,
    float* __restrict__ g_hs, float* __restrict__ g_ht,
    float* __restrict__ gs1, float* __restrict__ gt1,
    float* __restrict__ gt2, float* __restrict__ gs2) {
  __shared__ int s_o[4][CAP];
  __shared__ float s_x[4][CAP][NH];
  __shared__ float WsT[NC][HFO];  // transposed [class][k]
  __shared__ float WtT[NC][HFO];
  for (int i = threadIdx.x; i < HFO * NC; i += 256) {
    WsT[i & 7][i >> 3] = Wso[i];
    WtT[i & 7][i >> 3] = Wto[i];
  }
  __syncthreads();
  const int wv = threadIdx.x >> 6;
  const int lane = threadIdx.x & 63;
  const int w = blockIdx.x * 4 + wv;
  if (w >= GN) return;
  const int h = lane >> 3;
  const int j = lane & 7;
  int* s_o_w = &s_o[wv][0];
  float* s_x_w = &s_x[wv][0][0];
  // dir 0: h_ts (segment by target, gather hs[source]); dir 1: h_st
  float4 o_ts = agg_dir(off_t, adj_t, s1, t1, hs16, w, h, j, lane, s_o_w, s_x_w);
  float4 o_st = agg_dir(off_s, adj_s, t2, s2, ht16, w, h, j, lane, s_o_w, s_x_w);
  // fused layer-2 projection: g_hs = out_ts @ Ws_o, g_ht = out_st @ Wt_o
  const int k0 = lane * 4;
  float as[NC], at[NC];
#pragma unroll
  for (int c = 0; c < NC; ++c) {
    float4 wsv = *reinterpret_cast<const float4*>(&WsT[c][k0]);
    float4 wtv = *reinterpret_cast<const float4*>(&WtT[c][k0]);
    as[c] = o_ts.x * wsv.x + o_ts.y * wsv.y + o_ts.z * wsv.z + o_ts.w * wsv.w;
    at[c] = o_st.x * wtv.x + o_st.y * wtv.y + o_st.z * wtv.z + o_st.w * wtv.w;
  }
#pragma unroll
  for (int k = 1; k < 64; k <<= 1) {
#pragma unroll
    for (int c = 0; c < NC; ++c) {
      as[c] += __shfl_xor(as[c], k);
      at[c] += __shfl_xor(at[c], k);
    }
  }
  if (lane == 0) {
    *reinterpret_cast<float4*>(g_hs + (size_t)w * NC) = make_float4(as[0], as[1], as[2], as[3]);
    *reinterpret_cast<float4*>(g_hs + (size_t)w * NC + 4) = make_float4(as[4], as[5], as[6], as[7]);
    *reinterpret_cast<float4*>(g_ht + (size_t)w * NC) = make_float4(at[0], at[1], at[2], at[3]);
    *reinterpret_cast<float4*>(g_ht + (size_t)w * NC + 4) = make_float4(at[4], at[5], at[6], at[7]);
    float v1 = 0.f, v2 = 0.f, v3 = 0.f, v4 = 0.f;
#pragma unroll
    for (int c = 0; c < NC; ++c) {
      v1 = fmaf(as[c], a1o[c], v1);
      v2 = fmaf(at[c], a1o[NC + c], v2);
      v3 = fmaf(at[c], a2o[c], v3);
      v4 = fmaf(as[c], a2o[NC + c], v4);
    }
    gs1[w] = v1; gt1[w] = v2; gt2[w] = v3; gs2[w] = v4;
  }
}

// ---- layer-2 aggregation + ELU + log_softmax, both directions in one launch ----
__global__ __launch_bounds__(256) void agg2_kernel(
    const int* __restrict__ off_t, const int* __restrict__ adj_t,
    const float* __restrict__ gs1, const float* __restrict__ gt1, const float* __restrict__ g_hs,
    const int* __restrict__ off_s, const int* __restrict__ adj_s,
    const float* __restrict__ gt2, const float* __restrict__ gs2, const float* __restrict__ g_ht,
    float* __restrict__ d_out) {
  __shared__ int s_o[4][CAP];
  __shared__ float s_w[4][CAP];
  const int wv = threadIdx.x >> 6;
  const int lane = threadIdx.x & 63;
  const int gw = blockIdx.x * 4 + wv;
  const bool dir = gw >= GN;
  const int w = dir ? gw - GN : gw;
  const int* __restrict__ off = dir ? off_s : off_t;
  const int* __restrict__ adj = dir ? adj_s : adj_t;
  const float* __restrict__ sA = dir ? gt2 : gs1;
  const float* __restrict__ sB = dir ? gs2 : gt1;
  const float* __restrict__ feat = dir ? g_ht : g_hs;
  float* __restrict__ out = dir ? d_out : d_out + (size_t)GN * NC;

  const int beg = off[w];
  const int d = off[w + 1] - beg;
  const int c = lane & 7;
  const int g = lane >> 3;
  float acc = 0.f;
  if (d > 0) {
    const float sBn = sB[w];
    float m = -1e30f;
    for (int p = lane; p < d; p += 64) {
      int o = adj[beg + p];
      float x = sA[o] + sBn;
      x = x >= 0.f ? x : 0.1f * x;
      if (p < CAP) { s_o[wv][p] = o; s_w[wv][p] = x; }
      m = fmaxf(m, x);
    }
#pragma unroll
    for (int k = 1; k < 64; k <<= 1) m = fmaxf(m, __shfl_xor(m, k));
    lds_fence();
    const int dc = d < CAP ? d : CAP;
    float sum = 0.f;
    for (int p = lane; p < dc; p += 64) {
      float e = __expf(s_w[wv][p] - m);
      s_w[wv][p] = e;
      sum += e;
    }
    for (int p = CAP + lane; p < d; p += 64) {
      int o = adj[beg + p];
      float x = sA[o] + sBn;
      x = x >= 0.f ? x : 0.1f * x;
      sum += __expf(x - m);
    }
#pragma unroll
    for (int k = 1; k < 64; k <<= 1) sum += __shfl_xor(sum, k);
    float inv = 1.f / sum;
    lds_fence();
    for (int p = g; p < dc; p += 8)
      acc = fmaf(s_w[wv][p], feat[(size_t)s_o[wv][p] * NC + c], acc);
    for (int p = dc + g; p < d; p += 8) {  // overflow
      int o = adj[beg + p];
      float x = sA[o] + sBn;
      x = x >= 0.f ? x : 0.1f * x;
      acc = fmaf(__expf(x - m), feat[(size_t)o * NC + c], acc);
    }
#pragma unroll
    for (int k = 8; k < 64; k <<= 1) acc += __shfl_xor(acc, k);
    acc *= inv;
  }
  acc = acc > 0.f ? acc : __expf(acc) - 1.f;  // ELU
  float mx = acc;
#pragma unroll
  for (int k = 1; k < 8; k <<= 1) mx = fmaxf(mx, __shfl_xor(mx, k));
  float ex = __expf(acc - mx);
  float se = ex;
#pragma unroll
  for (int k = 1; k < 8; k <<= 1) se += __shfl_xor(se, k);
  float r = acc - mx - logf(se);
  if (lane < NC) out[(size_t)w * NC + lane] = r;
}

extern "C" void kernel_launch(void* const* d_in, const int* in_sizes, int n_in,
                              void* d_out, int out_size, void* d_ws, size_t ws_size,
                              hipStream_t stream) {
  const float* x_source = (const float*)d_in[0];
  const float* x_target = (const float*)d_in[1];
  const int* edge_t = (const int*)d_in[2];
  const int* edge_s = (const int*)d_in[3];
  const float* Ws_h = (const float*)d_in[4];
  const float* Wt_h = (const float*)d_in[5];
  const float* a1_h = (const float*)d_in[6];
  const float* a2_h = (const float*)d_in[7];
  const float* Ws_o = (const float*)d_in[8];
  const float* Wt_o = (const float*)d_in[9];
  const float* a1_o = (const float*)d_in[10];
  const float* a2_o = (const float*)d_in[11];
  float* out = (float*)d_out;
  (void)in_sizes; (void)n_in; (void)out_size; (void)ws_size;

  char* wptr = (char*)d_ws;
  auto alloc = [&](size_t bytes) -> void* {
    void* p = (void*)wptr;
    wptr += (bytes + 255) & ~(size_t)255;
    return p;
  };
  ushort* hs16 = (ushort*)alloc((size_t)GN * HFO * 2);
  ushort* ht16 = (ushort*)alloc((size_t)GN * HFO * 2);
  float* s1 = (float*)alloc((size_t)GN * NH * 4);
  float* t1 = (float*)alloc((size_t)GN * NH * 4);
  float* s2 = (float*)alloc((size_t)GN * NH * 4);
  float* t2 = (float*)alloc((size_t)GN * NH * 4);
  float* g_hs = (float*)alloc((size_t)GN * NC * 4);
  float* g_ht = (float*)alloc((size_t)GN * NC * 4);
  float* gs1 = (float*)alloc((size_t)GN * 4);
  float* gt1 = (float*)alloc((size_t)GN * 4);
  float* gt2 = (float*)alloc((size_t)GN * 4);
  float* gs2 = (float*)alloc((size_t)GN * 4);
  int* cnt_t = (int*)alloc((size_t)2 * GN * 4);
  int* cnt_s = cnt_t + GN;
  int* off_t = (int*)alloc((size_t)(GN + 1) * 4);
  int* off_s = (int*)alloc((size_t)(GN + 1) * 4);
  int* cur_t = (int*)alloc((size_t)GN * 4);
  int* cur_s = (int*)alloc((size_t)GN * 4);
  int* adj_t = (int*)alloc((size_t)GE * 4);
  int* adj_s = (int*)alloc((size_t)GE * 4);

  hipMemsetAsync(cnt_t, 0, (size_t)2 * GN * 4, stream);

  gemm1_kernel<<<dim3(391, 2, 2), 256, 0, stream>>>(
      x_source, x_target, Ws_h, Wt_h, a1_h, a2_h,
      hs16, ht16, s1, t1, s2, t2);
  count_kernel<<<782, 256, 0, stream>>>(edge_t, edge_s, cnt_t, cnt_s);
  scan_kernel<<<2, 1024, 0, stream>>>(cnt_t, off_t, cur_t, cnt_s, off_s, cur_s);
  scatter_kernel<<<782, 256, 0, stream>>>(edge_t, edge_s, cur_t, cur_s, adj_t, adj_s);

  agg1_kernel<<<12500, 256, 0, stream>>>(off_t, adj_t, s1, t1,
                                         off_s, adj_s, t2, s2,
                                         hs16, ht16, Ws_o, Wt_o, a1_o, a2_o,
                                         g_hs, g_ht, gs1, gt1, gt2, gs2);
  agg2_kernel<<<25000, 256, 0, stream>>>(off_t, adj_t, gs1, gt1, g_hs,
                                         off_s, adj_s, gt2, gs2, g_ht, out);
}